// Round 1
// baseline (141.383 us; speedup 1.0000x reference)
//
#include <hip/hip_runtime.h>

// TripletLossMultipleMargins: mean(relu(|a-p|^2 - |a-n|^2 + M[al, nl]))
// B=1048576, D=64, N_CLASSES=10. Memory-bound streaming reduction.

namespace {
constexpr int kB           = 1048576;
constexpr int kNC          = 10;
constexpr int kBlock       = 256;
constexpr int kLanesPerRow = 16;                     // 16 lanes x float4 = 64 floats = D
constexpr int kRowsPerBlk  = kBlock / kLanesPerRow;  // 16 rows per block-iteration
constexpr int kGrid        = 2048;                   // kGrid*kRowsPerBlk = 32768 divides kB
}

__global__ __launch_bounds__(kBlock) void triplet_partial_kernel(
    const float4* __restrict__ a,
    const float4* __restrict__ p,
    const float4* __restrict__ n,
    const int*    __restrict__ alab,
    const int*    __restrict__ nlab,
    const float*  __restrict__ mm,
    float*        __restrict__ partials)
{
    __shared__ float s_m[kNC * kNC];
    for (int i = threadIdx.x; i < kNC * kNC; i += kBlock) s_m[i] = mm[i];
    __syncthreads();

    const int j   = threadIdx.x & (kLanesPerRow - 1);
    const int rib = threadIdx.x / kLanesPerRow;

    float acc = 0.0f;

    // kB % (gridDim*kRowsPerBlk) == 0 -> every r is in-bounds, no tail branch.
    for (int base = blockIdx.x * kRowsPerBlk; base < kB;
         base += gridDim.x * kRowsPerBlk) {
        const int r   = base + rib;
        const int idx = r * kLanesPerRow + j;   // float4 index, max 16M < 2^31

        const float4 av = a[idx];
        const float4 pv = p[idx];
        const float4 nv = n[idx];

        float d;
        float dp = 0.0f, dn = 0.0f;
        d = av.x - pv.x; dp = fmaf(d, d, dp);
        d = av.y - pv.y; dp = fmaf(d, d, dp);
        d = av.z - pv.z; dp = fmaf(d, d, dp);
        d = av.w - pv.w; dp = fmaf(d, d, dp);
        d = av.x - nv.x; dn = fmaf(d, d, dn);
        d = av.y - nv.y; dn = fmaf(d, d, dn);
        d = av.z - nv.z; dn = fmaf(d, d, dn);
        d = av.w - nv.w; dn = fmaf(d, d, dn);

        float diff = dp - dn;           // reduce one value, not two
        #pragma unroll
        for (int m = 8; m >= 1; m >>= 1) diff += __shfl_xor(diff, m, 64);

        if (j == 0) {
            const float margin = s_m[alab[r] * kNC + nlab[r]];
            const float loss   = diff + margin;
            acc += (loss > 0.0f) ? loss : 0.0f;
        }
    }

    // block-wide reduction (acc is zero on j!=0 lanes; summing all is fine)
    #pragma unroll
    for (int m = 32; m >= 1; m >>= 1) acc += __shfl_xor(acc, m, 64);
    __shared__ float s_red[kBlock / 64];
    if ((threadIdx.x & 63) == 0) s_red[threadIdx.x >> 6] = acc;
    __syncthreads();
    if (threadIdx.x == 0) {
        float s = 0.0f;
        #pragma unroll
        for (int w = 0; w < kBlock / 64; ++w) s += s_red[w];
        partials[blockIdx.x] = s;
    }
}

__global__ __launch_bounds__(256) void triplet_finalize_kernel(
    const float* __restrict__ partials, float* __restrict__ out, int g)
{
    float acc = 0.0f;
    for (int i = threadIdx.x; i < g; i += 256) acc += partials[i];
    #pragma unroll
    for (int m = 32; m >= 1; m >>= 1) acc += __shfl_xor(acc, m, 64);
    __shared__ float s_red[4];
    if ((threadIdx.x & 63) == 0) s_red[threadIdx.x >> 6] = acc;
    __syncthreads();
    if (threadIdx.x == 0) {
        out[0] = (s_red[0] + s_red[1] + s_red[2] + s_red[3]) * (1.0f / (float)kB);
    }
}

extern "C" void kernel_launch(void* const* d_in, const int* in_sizes, int n_in,
                              void* d_out, int out_size, void* d_ws, size_t ws_size,
                              hipStream_t stream) {
    const float4* a    = (const float4*)d_in[0];
    const float4* p    = (const float4*)d_in[1];
    const float4* n    = (const float4*)d_in[2];
    const int*    alab = (const int*)d_in[3];
    const int*    nlab = (const int*)d_in[4];
    const float*  mm   = (const float*)d_in[5];

    float* partials = (float*)d_ws;           // kGrid floats, fully overwritten
    float* out      = (float*)d_out;

    triplet_partial_kernel<<<kGrid, kBlock, 0, stream>>>(a, p, n, alab, nlab, mm, partials);
    triplet_finalize_kernel<<<1, 256, 0, stream>>>(partials, out, kGrid);
}